// Round 2
// baseline (1624.005 us; speedup 1.0000x reference)
//
#include <hip/hip_runtime.h>

// Fused StyleGAN2 blur(4x4 FIR, pad 2/2) + 3x3 stride-2 VALID conv + bias.
// x: [8,256,256,128] f32 NHWC, cw: [3,3,128,256] f32 HWIO, cb: [256], bk: [4]
// out: [8,128,128,256] f32.
// Strategy: zero-workspace fused kernel. Per block: output tile 8x16 spatial
// x 128 cout. Loop ci in chunks of 8: stage x patch -> LDS, blur -> y LDS,
// stage W chunk -> LDS (union with x region), 72-step outer-product GEMM with
// 8x8 per-thread micro-tile (fp32 vector FMA; no fp32 MFMA on CDNA4).

#define CIN  128
#define COUT 256
#define HH   256
#define WWID 256
#define OHH  128
#define OWW  128

#define TOH 8     // output rows per block
#define TOW 16    // output cols per block
#define TN  128   // cout per block
#define CK  8     // ci per chunk
#define YR  17    // y patch rows  (2*TOH+1)
#define YC  33    // y patch cols  (2*TOW+1)
#define YCP 34    // padded pitch
#define XR  20    // x patch rows  (YR+3)
#define XC  36    // x patch cols  (YC+3)
#define KC  72    // K per chunk = 9*CK

__global__ __launch_bounds__(256, 2)
void fused_blur_conv_down(const float* __restrict__ x,
                          const float* __restrict__ cw,
                          const float* __restrict__ cb,
                          const float* __restrict__ bk,
                          float* __restrict__ out)
{
    __shared__ float bufA[KC * TN];        // 9216 f (36.9 KB); also holds x patch (5760 f)
    __shared__ float yb[CK * YR * YCP];    // 4624 f (18.5 KB)

    const int tid = threadIdx.x;
    int bid = blockIdx.x;
    const int nb  = bid & 1;  bid >>= 1;          // cout half
    const int b   = bid >> 7;                     // batch
    const int t2  = bid & 127;
    const int oh0 = (t2 >> 3) * TOH;              // 16 oh tiles
    const int ow0 = (t2 & 7)  * TOW;              // 8 ow tiles
    const int co0 = nb * TN;

    // normalized blur taps: k2d[fh][fw] = bk[fh]*bk[fw] / (sum bk)^2
    const float t0 = bk[0], t1 = bk[1], t2v = bk[2], t3 = bk[3];
    const float s  = t0 + t1 + t2v + t3;
    const float inv = 1.0f / (s * s);
    const float v0 = t0 * inv, v1 = t1 * inv, v2 = t2v * inv, v3 = t3 * inv;

    const int tm   = tid >> 4;          // 0..15 -> which 8 output pixels
    const int tn   = tid & 15;          // 0..15 -> which 8 cout
    const int moh  = tm >> 1;           // 0..7
    const int mow0 = (tm & 1) * 8;      // 0 or 8

    float acc[8][8];
    #pragma unroll
    for (int i = 0; i < 8; ++i)
        #pragma unroll
        for (int j = 0; j < 8; ++j) acc[i][j] = 0.f;

    const int gxr0 = 2 * oh0 - 2;
    const int gxc0 = 2 * ow0 - 2;

    for (int ci0 = 0; ci0 < CIN; ci0 += CK) {
        // ---- phase 1: x patch -> bufA  ([ci][xr][xc], plane stride 720) ----
        for (int idx = tid; idx < XR * XC * 2; idx += 256) {
            const int p    = idx >> 1;        // pixel 0..719
            const int part = idx & 1;         // which 4 channels
            const int xr = p / XC;
            const int xc = p - xr * XC;
            const int gr = gxr0 + xr;
            const int gc = gxc0 + xc;
            float4 v = make_float4(0.f, 0.f, 0.f, 0.f);
            if ((unsigned)gr < HH && (unsigned)gc < WWID) {
                v = *(const float4*)(x + ((((size_t)b * HH + gr) * WWID + gc) * CIN + ci0 + part * 4));
            }
            float* d = &bufA[(part * 4) * (XR * XC) + p];
            d[0]        = v.x;
            d[720]      = v.y;
            d[1440]     = v.z;
            d[2160]     = v.w;
        }
        __syncthreads();

        // ---- phase 2: blur -> yb  ([ci][r][c] pitch 34) ----
        {
            const int ciL  = tid >> 5;            // 0..7
            const int lane = tid & 31;
            const float* xp0 = &bufA[ciL * (XR * XC)];
            float* yp0 = &yb[ciL * (YR * YCP)];
            #pragma unroll 2
            for (int it = 0; it < 18; ++it) {
                const int pos = lane + (it << 5);
                if (pos < YR * YC) {
                    const int r = pos / YC;
                    const int c = pos - r * YC;
                    const float* xp = xp0 + r * XC + c;
                    float h0 = t0*xp[0] + t1*xp[1] + t2v*xp[2] + t3*xp[3]; xp += XC;
                    float h1 = t0*xp[0] + t1*xp[1] + t2v*xp[2] + t3*xp[3]; xp += XC;
                    float h2 = t0*xp[0] + t1*xp[1] + t2v*xp[2] + t3*xp[3]; xp += XC;
                    float h3 = t0*xp[0] + t1*xp[1] + t2v*xp[2] + t3*xp[3];
                    yp0[r * YCP + c] = v0*h0 + v1*h1 + v2*h2 + v3*h3;
                }
            }
        }
        __syncthreads();

        // ---- phase 3: W chunk -> bufA  ([k=khkw*8+cil][co] 72x128) ----
        for (int idx = tid; idx < (KC * TN) / 4; idx += 256) {   // 2304 float4, 9/thread
            const int row  = idx >> 5;      // 0..71
            const int c4   = idx & 31;
            const int khkw = row >> 3;      // 0..8
            const int cil  = row & 7;
            const float4 v = *(const float4*)(cw + (((size_t)khkw * CIN + ci0 + cil) * COUT + co0 + c4 * 4));
            ((float4*)bufA)[idx] = v;
        }
        __syncthreads();

        // ---- phase 4: GEMM (K = 72) ----
        for (int kh = 0; kh < 3; ++kh) {
            for (int kw = 0; kw < 3; ++kw) {
                const float* ybase = &yb[(2 * moh + kh) * YCP + 2 * mow0 + kw];
                const float* wbase = &bufA[((kh * 3 + kw) * CK) * TN + tn * 8];
                #pragma unroll
                for (int cil = 0; cil < CK; ++cil) {
                    const float* ap = ybase + cil * (YR * YCP);
                    const float* bp = wbase + cil * TN;
                    float aa[8];
                    #pragma unroll
                    for (int i = 0; i < 8; ++i) aa[i] = ap[2 * i];
                    const float4 q0 = *(const float4*)bp;
                    const float4 q1 = *(const float4*)(bp + 4);
                    const float bb[8] = {q0.x, q0.y, q0.z, q0.w, q1.x, q1.y, q1.z, q1.w};
                    #pragma unroll
                    for (int i = 0; i < 8; ++i)
                        #pragma unroll
                        for (int j = 0; j < 8; ++j)
                            acc[i][j] += aa[i] * bb[j];
                }
            }
        }
        __syncthreads();
    }

    // ---- epilogue: bias + store ----
    const float4 bias0 = *(const float4*)(cb + co0 + tn * 8);
    const float4 bias1 = *(const float4*)(cb + co0 + tn * 8 + 4);
    const int oh = oh0 + moh;
    #pragma unroll
    for (int i = 0; i < 8; ++i) {
        const int ow = ow0 + mow0 + i;
        float* o = out + ((((size_t)b * OHH + oh) * OWW + ow) * COUT + co0 + tn * 8);
        float4 r0, r1;
        r0.x = acc[i][0] + bias0.x; r0.y = acc[i][1] + bias0.y;
        r0.z = acc[i][2] + bias0.z; r0.w = acc[i][3] + bias0.w;
        r1.x = acc[i][4] + bias1.x; r1.y = acc[i][5] + bias1.y;
        r1.z = acc[i][6] + bias1.z; r1.w = acc[i][7] + bias1.w;
        *(float4*)o       = r0;
        *(float4*)(o + 4) = r1;
    }
}

extern "C" void kernel_launch(void* const* d_in, const int* in_sizes, int n_in,
                              void* d_out, int out_size, void* d_ws, size_t ws_size,
                              hipStream_t stream)
{
    const float* x  = (const float*)d_in[0];
    const float* cw = (const float*)d_in[1];
    const float* cb = (const float*)d_in[2];
    const float* bk = (const float*)d_in[3];
    float* out = (float*)d_out;

    // grid: 8 batches * 16 ohT * 8 owT * 2 cout-halves = 2048 blocks
    const int grid = 8 * 16 * 8 * 2;
    fused_blur_conv_down<<<grid, 256, 0, stream>>>(x, cw, cb, bk, out);
}

// Round 4
// 612.779 us; speedup vs baseline: 2.6502x; 2.6502x over previous
//
#include <hip/hip_runtime.h>

// Fused StyleGAN2 FIR-blur(4x4, pad2) + 3x3 stride-2 conv + bias via fp16 MFMA.
// x:[8,256,256,128]f32 NHWC, cw:[3,3,128,256]f32 HWIO, cb:[256], bk:[4] -> out:[8,128,128,256]f32
//
// Accuracy: activations split y = hi + lo (two fp16), weights single fp16.
// GEMM view: out[128 pixel x 128 co per block] = A[128, K] * B[K, 128],
//   K per ci16-chunk = 9(khkw) x 16(ci) x 2(plane) = 288 = 9 MFMA K=32 steps.
// mfma_f32_16x16x32_f16 layouts: A: row=lane&15, k=(lane>>4)*8+j;
//   B: col=lane&15, same k; D: col=lane&15, row=(lane>>4)*4+reg.
// y LDS lines (16B = 8 f16): L = plane*1139 + r*67 + c*2 + cihalf, stored at
//   byte (L<<4) ^ (((L<<4)>>3)&0x70)  -- XOR bits4-6 with bits7-9: BIJECTIVE
//   (round-3 bug: key derived from c aliased with low line bits -> collisions).
//   A-read (c=2*l15+kw, 4-line lane stride) lands 2-way per bank slot = free.

typedef _Float16 f16;
typedef _Float16 f16x8 __attribute__((ext_vector_type(8)));
typedef float f32x4 __attribute__((ext_vector_type(4)));

#define YBYTES 36480            // 2280 lines * 16B (max L 2276, group-capped < 2280)
#define WREG   42240            // max(H = 20*33*4*16 = 42240, W = 128*19*16 = 38912)

// ---- kernel A: W fp32 [khkw][ci][co] -> fp16 [chunk8][co256][k144], k = khkw*16 + (ci&15)
__global__ void wconv(const float* __restrict__ w, f16* __restrict__ wt) {
    int idx = blockIdx.x * 256 + threadIdx.x;      // 294912 total
    int row = idx / 144;                           // chunk*256 + co
    int k   = idx - row * 144;
    int khkw = k >> 4;
    int ci   = ((row >> 8) << 4) + (k & 15);
    int co   = row & 255;
    wt[idx] = (f16)w[(khkw << 15) + (ci << 8) + co];
}

__device__ __forceinline__ float4 ldx(const float* row, int gc, bool rok) {
    if (rok && (unsigned)gc < 256u) return *(const float4*)(row + gc * 128);
    return make_float4(0.f, 0.f, 0.f, 0.f);
}

__global__ __launch_bounds__(256, 2)
void fused_mfma(const float* __restrict__ x, const f16* __restrict__ wt,
                const float* __restrict__ cb, const float* __restrict__ bk,
                float* __restrict__ out)
{
    __shared__ char smem[YBYTES + WREG];

    const int tid = threadIdx.x;
    // XCD-aware swizzle: each XCD gets 256 logical-consecutive blocks = one batch image.
    const int hb = blockIdx.x;
    const int lb = (hb & 7) * 256 + (hb >> 3);
    const int cohalf = lb & 1;
    const int t  = lb >> 1;
    const int b  = t >> 7;
    const int oh0 = ((t >> 3) & 15) * 8;
    const int ow0 = (t & 7) * 16;
    const int co0 = cohalf * 128;

    const float t0 = bk[0], t1 = bk[1], t2 = bk[2], t3 = bk[3];
    const float sum = t0 + t1 + t2 + t3;
    const float inv = 1.0f / (sum * sum);
    const float v0 = t0 * inv, v1 = t1 * inv, v2 = t2 * inv, v3 = t3 * inv;

    const int lane = tid & 63;
    const int wave = tid >> 6;
    const int wm = wave >> 1, wn = wave & 1;      // 2x2 waves, wave tile 64x64
    const int l15 = lane & 15;
    const int lg  = lane >> 4;
    const int plane  = lg & 1;                    // A hi/lo plane
    const int cihalf = lg >> 1;                   // which 8 of the 16 ci

    // A-read per-thread byte constants (linear, pre-swizzle)
    const int baseA = plane * 18224 + cihalf * 16;
    int cbyteA[3];
    #pragma unroll
    for (int kw = 0; kw < 3; ++kw) cbyteA[kw] = (2 * l15 + kw) * 32;

    // horizontal-pass map: 240 threads = 20 rows x 3 col-segs x 4 ci4-parts
    const bool hp_act = tid < 240;
    const int hp_rr   = tid / 12;
    const int hp_w    = tid - hp_rr * 12;
    const int hp_seg  = hp_w >> 2;
    const int hp_part = hp_w & 3;

    const int gxr0 = 2 * oh0 - 2;
    const int gxc0 = 2 * ow0 - 2;

    f32x4 acc[4][4];
    #pragma unroll
    for (int i = 0; i < 4; ++i)
        #pragma unroll
        for (int j = 0; j < 4; ++j)
            acc[i][j] = (f32x4){0.f, 0.f, 0.f, 0.f};

    for (int chunk = 0; chunk < 8; ++chunk) {
        const int ci0 = chunk * 16;

        // ---- W prefetch to regs (hides L2 latency under blur phases) ----
        f32x4 wreg[9];
        int wco[9], wku[9];
        #pragma unroll
        for (int it = 0; it < 9; ++it) {
            int idx = tid + it * 256;              // < 2304 exactly
            int co = idx / 18;
            int ku = idx - co * 18;
            wco[it] = co; wku[it] = ku;
            wreg[it] = *(const f32x4*)((const char*)wt +
                        (((size_t)((chunk * 256 + co0 + co) * 18 + ku)) << 4));
        }

        // ---- ph1: horizontal FIR  x(global) -> H(LDS fp32 [rr][c][ci16]) ----
        if (hp_act) {
            const int gr = gxr0 + hp_rr;
            const bool rok = (unsigned)gr < 256u;
            const float* xrow = x + (((size_t)b * 256 + (rok ? gr : 0)) * 256) * 128
                                  + ci0 + hp_part * 4;
            const int xc0 = hp_seg * 11;
            float4 w0 = ldx(xrow, gxc0 + xc0 + 0, rok);
            float4 w1 = ldx(xrow, gxc0 + xc0 + 1, rok);
            float4 w2 = ldx(xrow, gxc0 + xc0 + 2, rok);
            #pragma unroll
            for (int c = 0; c < 11; ++c) {
                float4 w3 = ldx(xrow, gxc0 + xc0 + c + 3, rok);
                float4 h;
                h.x = t0 * w0.x + t1 * w1.x + t2 * w2.x + t3 * w3.x;
                h.y = t0 * w0.y + t1 * w1.y + t2 * w2.y + t3 * w3.y;
                h.z = t0 * w0.z + t1 * w1.z + t2 * w2.z + t3 * w3.z;
                h.w = t0 * w0.w + t1 * w1.w + t2 * w2.w + t3 * w3.w;
                *(float4*)(smem + YBYTES +
                    (((hp_rr * 33 + xc0 + c) * 4 + hp_part) << 4)) = h;
                w0 = w1; w1 = w2; w2 = w3;
            }
        }
        __syncthreads();

        // ---- ph2: vertical FIR  H -> y fp16 hi/lo (bijective-swizzled lines) ----
        #pragma unroll
        for (int it = 0; it < 5; ++it) {
            int l = tid + it * 256;
            if (l < 1122) {                        // 17 r * 33 c * 2 cihalf
                int r = l / 66;
                int rem = l - r * 66;
                int c  = rem >> 1;
                int ch = rem & 1;
                const char* Hb = smem + YBYTES;
                float ya[8];
                #pragma unroll
                for (int i = 0; i < 8; ++i) ya[i] = 0.f;
                #pragma unroll
                for (int dr = 0; dr < 4; ++dr) {
                    const float vv = (dr == 0) ? v0 : (dr == 1) ? v1 : (dr == 2) ? v2 : v3;
                    f32x4 ha = *(const f32x4*)(Hb + ((((r + dr) * 33 + c) * 4 + ch * 2) << 4));
                    f32x4 hb2 = *(const f32x4*)(Hb + ((((r + dr) * 33 + c) * 4 + ch * 2 + 1) << 4));
                    ya[0] += vv * ha[0]; ya[1] += vv * ha[1];
                    ya[2] += vv * ha[2]; ya[3] += vv * ha[3];
                    ya[4] += vv * hb2[0]; ya[5] += vv * hb2[1];
                    ya[6] += vv * hb2[2]; ya[7] += vv * hb2[3];
                }
                f16x8 hi8, lo8;
                #pragma unroll
                for (int i = 0; i < 8; ++i) {
                    f16 h = (f16)ya[i];
                    hi8[i] = h;
                    lo8[i] = (f16)(ya[i] - (float)h);
                }
                int line = r * 67 + c * 2 + ch;
                int linH = line << 4;
                int linL = (line + 1139) << 4;
                *(f16x8*)(smem + (linH ^ ((linH >> 3) & 0x70))) = hi8;
                *(f16x8*)(smem + (linL ^ ((linL >> 3) & 0x70))) = lo8;
            }
        }
        __syncthreads();

        // ---- ph3: W regs -> LDS [co][pitch 19 lines] ----
        #pragma unroll
        for (int it = 0; it < 9; ++it)
            *(f32x4*)(smem + YBYTES + ((wco[it] * 19 + wku[it]) << 4)) = wreg[it];
        __syncthreads();

        // ---- ph4: 9 MFMA K-steps (khkw = s uniform; lanes carry plane/cihalf) ----
        #pragma unroll
        for (int s = 0; s < 9; ++s) {
            const int kh = s / 3, kw = s % 3;      // compile-time
            f16x8 bf[4];
            #pragma unroll
            for (int nb = 0; nb < 4; ++nb)
                bf[nb] = *(const f16x8*)(smem + YBYTES +
                          (wn * 64 + nb * 16 + l15) * 304 + s * 32 + cihalf * 16);
            f16x8 af[4];
            #pragma unroll
            for (int mb = 0; mb < 4; ++mb) {
                int r = 2 * (wm * 4 + mb) + kh;
                int lin = baseA + r * 1072 + cbyteA[kw];
                af[mb] = *(const f16x8*)(smem + (lin ^ ((lin >> 3) & 0x70)));
            }
            #pragma unroll
            for (int mb = 0; mb < 4; ++mb)
                #pragma unroll
                for (int nb = 0; nb < 4; ++nb)
                    acc[mb][nb] = __builtin_amdgcn_mfma_f32_16x16x32_f16(
                        af[mb], bf[nb], acc[mb][nb], 0, 0, 0);
        }
        __syncthreads();
    }

    // ---- epilogue: bias + store (D: col=l15, row=lg*4+reg) ----
    float bias[4];
    #pragma unroll
    for (int nb = 0; nb < 4; ++nb)
        bias[nb] = cb[co0 + wn * 64 + nb * 16 + l15];
    #pragma unroll
    for (int mb = 0; mb < 4; ++mb) {
        const int oh = oh0 + wm * 4 + mb;
        #pragma unroll
        for (int q = 0; q < 4; ++q) {
            const int ow = ow0 + lg * 4 + q;
            float* op = out + ((((size_t)b * 128 + oh) * 128 + ow) * 256)
                        + co0 + wn * 64 + l15;
            #pragma unroll
            for (int nb = 0; nb < 4; ++nb)
                op[nb * 16] = acc[mb][nb][q] + bias[nb];
        }
    }
}

extern "C" void kernel_launch(void* const* d_in, const int* in_sizes, int n_in,
                              void* d_out, int out_size, void* d_ws, size_t ws_size,
                              hipStream_t stream)
{
    const float* x  = (const float*)d_in[0];
    const float* cw = (const float*)d_in[1];
    const float* cb = (const float*)d_in[2];
    const float* bk = (const float*)d_in[3];
    float* out = (float*)d_out;
    f16* wt = (f16*)d_ws;                          // 589,824 B scratch

    wconv<<<1152, 256, 0, stream>>>(cw, wt);
    fused_mfma<<<2048, 256, 0, stream>>>(x, wt, cb, bk, out);
}